// Round 12
// baseline (152.173 us; speedup 1.0000x reference)
//
#include <hip/hip_runtime.h>
#include <hip/hip_bf16.h>

typedef __attribute__((ext_vector_type(8))) short short8;           // 8 bf16 (MFMA operand)
typedef __attribute__((ext_vector_type(8))) unsigned short ushort8; // data movement
typedef __attribute__((ext_vector_type(4))) float f32x4;
typedef __attribute__((ext_vector_type(4))) unsigned short u16x4;

#define MFMA16(a, b, c) __builtin_amdgcn_mfma_f32_16x16x32_bf16(a, b, c, 0, 0, 0)

__device__ __forceinline__ unsigned short f2bf(float f) {
  union { float f; unsigned u; } x; x.f = f;
  unsigned r = x.u + 0x7FFFu + ((x.u >> 16) & 1u);  // RNE
  return (unsigned short)(r >> 16);
}
__device__ __forceinline__ float bf2f(unsigned short h) {
  union { unsigned u; float f; } x; x.u = ((unsigned)h) << 16;
  return x.f;
}
__device__ __forceinline__ void load_lds16(const void* g, void* l) {
  __builtin_amdgcn_global_load_lds((const __attribute__((address_space(1))) void*)g,
                                   (__attribute__((address_space(3))) void*)l, 16, 0, 0);
}

// ---------------------------------------------------------------------------
// 1) fp32 -> bf16 conversion for x, w_qkv, w_proj
// ---------------------------------------------------------------------------
__global__ __launch_bounds__(256) void convert_all(
    const float* __restrict__ x, const float* __restrict__ wqkv, const float* __restrict__ wproj,
    unsigned short* __restrict__ xb, unsigned short* __restrict__ wqkvb,
    unsigned short* __restrict__ wprojb) {
  int i = blockIdx.x * 256 + threadIdx.x;
  const float4* src; unsigned short* dst; int o;
  if (i < 1048576) { src = (const float4*)x; dst = xb; o = i; }
  else if (i < 1048576 + 786432) { src = (const float4*)wqkv; dst = wqkvb; o = i - 1048576; }
  else { src = (const float4*)wproj; dst = wprojb; o = i - (1048576 + 786432); }
  float4 v = src[o];
  u16x4 r; r.x = f2bf(v.x); r.y = f2bf(v.y); r.z = f2bf(v.z); r.w = f2bf(v.w);
  *(u16x4*)(dst + (size_t)o * 4) = r;
}

// ---------------------------------------------------------------------------
// 2/6) NT GEMM: C[M,N] = A[M,K] * B[N,K]^T + bias, bf16 in, 128x128 tile,
//      BK=32, 4 waves each 64x64, global_load_lds w/ XOR-swizzled source.
// ---------------------------------------------------------------------------
template <bool OUT_BF16>
__global__ __launch_bounds__(256) void gemm_nt(
    const unsigned short* __restrict__ A, const unsigned short* __restrict__ Bm,
    const float* __restrict__ bias, void* __restrict__ Cout, int M, int N, int K) {
  __shared__ unsigned short As[128 * 32];
  __shared__ unsigned short Bs[128 * 32];
  const int t = threadIdx.x, w = t >> 6, l = t & 63;
  const int la = l & 15, lg = l >> 4;
  const int wm = w >> 1, wn = w & 1;
  const int m0 = blockIdx.y * 128, n0 = blockIdx.x * 128;

  const int r0 = t >> 2, c0 = (t & 3) ^ ((r0 >> 1) & 3);
  const int r1 = r0 + 64, c1 = (t & 3) ^ ((r1 >> 1) & 3);
  const unsigned short* a0 = A + (size_t)(m0 + r0) * K + c0 * 8;
  const unsigned short* a1 = A + (size_t)(m0 + r1) * K + c1 * 8;
  const unsigned short* b0 = Bm + (size_t)(n0 + r0) * K + c0 * 8;
  const unsigned short* b1 = Bm + (size_t)(n0 + r1) * K + c1 * 8;
  char* ldsA0 = (char*)As + w * 1024;
  char* ldsA1 = (char*)As + w * 1024 + 4096;
  char* ldsB0 = (char*)Bs + w * 1024;
  char* ldsB1 = (char*)Bs + w * 1024 + 4096;

  f32x4 acc[4][4] = {};
  int offA[4], offB[4];
#pragma unroll
  for (int f = 0; f < 4; ++f) {
    int ra = wm * 64 + f * 16 + la;
    offA[f] = ra * 64 + ((lg ^ ((ra >> 1) & 3)) * 16);
    int rb = wn * 64 + f * 16 + la;
    offB[f] = rb * 64 + ((lg ^ ((rb >> 1) & 3)) * 16);
  }

  for (int kt = 0; kt < K; kt += 32) {
    __syncthreads();
    load_lds16(a0 + kt, ldsA0);
    load_lds16(a1 + kt, ldsA1);
    load_lds16(b0 + kt, ldsB0);
    load_lds16(b1 + kt, ldsB1);
    __syncthreads();
    short8 af[4], bf[4];
#pragma unroll
    for (int f = 0; f < 4; ++f) af[f] = *(const short8*)((const char*)As + offA[f]);
#pragma unroll
    for (int f = 0; f < 4; ++f) bf[f] = *(const short8*)((const char*)Bs + offB[f]);
#pragma unroll
    for (int mf = 0; mf < 4; ++mf)
#pragma unroll
      for (int nf = 0; nf < 4; ++nf)
        acc[mf][nf] = MFMA16(af[mf], bf[nf], acc[mf][nf]);
  }

  const int colb = n0 + wn * 64 + la;
  const int rowb = m0 + wm * 64 + lg * 4;
#pragma unroll
  for (int nf = 0; nf < 4; ++nf) {
    const int col = colb + nf * 16;
    const float bv = bias[col];
#pragma unroll
    for (int mf = 0; mf < 4; ++mf)
#pragma unroll
      for (int r = 0; r < 4; ++r) {
        const int row = rowb + mf * 16 + r;
        float v = acc[mf][nf][r] + bv;
        if (OUT_BF16)
          ((unsigned short*)Cout)[(size_t)row * N + col] = f2bf(v);
        else
          ((float*)Cout)[(size_t)row * N + col] = v;
      }
  }
}

// ---------------------------------------------------------------------------
// 3) RMSNorm on q,k rows (64 elems each) of qkv, in place.
// ---------------------------------------------------------------------------
__global__ __launch_bounds__(256) void rmsnorm_qk(
    unsigned short* __restrict__ qkv, const float* __restrict__ qw, const float* __restrict__ kw) {
  const int t = threadIdx.x, w = t >> 6, l = t & 63;
  const int row = blockIdx.x * 32 + w * 8 + (l >> 3);  // 0..131071
  const int part = row >> 16;                           // 0=q, 1=k
  const int rem = row & 65535;
  const int bn = rem >> 4, h = rem & 15;
  unsigned short* p = qkv + (size_t)bn * 3072 + part * 1024 + h * 64 + (l & 7) * 8;
  ushort8 v = *(const ushort8*)p;
  float f[8]; float s = 0.f;
#pragma unroll
  for (int j = 0; j < 8; ++j) { f[j] = bf2f(v[j]); s += f[j] * f[j]; }
  s += __shfl_xor(s, 1); s += __shfl_xor(s, 2); s += __shfl_xor(s, 4);
  const float r = rsqrtf(s * (1.f / 64.f) + 1e-6f);
  const float* nw = part ? kw : qw;
  ushort8 o;
#pragma unroll
  for (int j = 0; j < 8; ++j) o[j] = f2bf(f[j] * r * nw[(l & 7) * 8 + j]);
  *(ushort8*)p = o;
}

// ---------------------------------------------------------------------------
// 4) Transpose V: qkv[b,n,2,h,d] -> vT[bh][d][n]
// ---------------------------------------------------------------------------
__global__ __launch_bounds__(256) void transpose_v(
    const unsigned short* __restrict__ qkv, unsigned short* __restrict__ vT) {
  __shared__ unsigned short tile[64][72];
  const int t = threadIdx.x;
  const int tn = blockIdx.x, bh = blockIdx.y;
  const int b = bh >> 4, h = bh & 15;
  for (int i = t; i < 512; i += 256) {
    const int n = i >> 3, c = i & 7;
    ushort8 v = *(const ushort8*)(qkv + (size_t)(b * 2048 + tn * 64 + n) * 3072 + 2048 + h * 64 + c * 8);
    *(ushort8*)&tile[n][c * 8] = v;
  }
  __syncthreads();
  for (int i = t; i < 512; i += 256) {
    const int d = i >> 3, c = i & 7;
    ushort8 o;
#pragma unroll
    for (int j = 0; j < 8; ++j) o[j] = tile[c * 8 + j][d];
    *(ushort8*)(vT + (size_t)(bh * 64 + d) * 2048 + tn * 64 + c * 8) = o;
  }
}

// ---------------------------------------------------------------------------
// 5) Flash attention — BK=128: TWO 64-key subtiles per monolithic stage phase
//    (the only proven staging pattern). Independent subtile chains give
//    within-wave MFMA/VALU overlap; barrier count halves (32 -> 16).
//    Ps: per-wave flat [16 q][8 chunks] with chunk XOR-swizzle c^(la&7)
//    (2-way = free on write & read). LDS total = 40960 B -> 4 blocks/CU.
// ---------------------------------------------------------------------------
__global__ __launch_bounds__(256) void attn_fwd(
    const unsigned short* __restrict__ qkv, const unsigned short* __restrict__ vT,
    unsigned short* __restrict__ outb) {
  __shared__ unsigned short Ks[2][64 * 64];
  __shared__ unsigned short Vs[2][64 * 64];
  __shared__ unsigned short Ps[4][16][64];  // flat, XOR-swizzled chunks
  const int t = threadIdx.x, w = t >> 6, l = t & 63;
  const int la = l & 15, lg = l >> 4;
  const int q0 = blockIdx.x * 64, bh = blockIdx.y;
  const int b = bh >> 4, h = bh & 15;

  // Q fragment (B-operand of swapped QK^T: col=q=la, k=d=lg*8+j)
  const int qrow = q0 + w * 16 + la;
  const unsigned short* qp = qkv + (size_t)(b * 2048 + qrow) * 3072 + h * 64;
  const short8 qa0 = *(const short8*)(qp + lg * 8);
  const short8 qa1 = *(const short8*)(qp + 32 + lg * 8);

  // staging sources: per 64-key tile, rows of 8 chunks, swizzle c ^= (r&7)
  const int r0 = t >> 3, c0 = (t & 7) ^ (r0 & 7);
  const int r1 = r0 + 32, c1 = (t & 7) ^ (r1 & 7);
  const unsigned short* k0p = qkv + (size_t)(b * 2048 + r0) * 3072 + 1024 + h * 64 + c0 * 8;
  const unsigned short* k1p = qkv + (size_t)(b * 2048 + r1) * 3072 + 1024 + h * 64 + c1 * 8;
  const unsigned short* v0p = vT + (size_t)(bh * 64 + r0) * 2048 + c0 * 8;
  const unsigned short* v1p = vT + (size_t)(bh * 64 + r1) * 2048 + c1 * 8;

  f32x4 accO[4] = {};
  float lsum = 0.f;
  const float SC = 0.125f * 1.44269504f;  // scale * log2(e)
  const float M = 12.0f;                  // static max bound (|q.k|<=64.5 -> |s*SC|<=11.63)

  char* psBase = (char*)Ps + w * 2048 + la * 128;
  const int swzW[4] = {  // write chunk slot per nf: (nf*2 + (lg>>1)) ^ (la&7)
      ((0 * 2 + (lg >> 1)) ^ (la & 7)) * 16 + (lg & 1) * 8,
      ((1 * 2 + (lg >> 1)) ^ (la & 7)) * 16 + (lg & 1) * 8,
      ((2 * 2 + (lg >> 1)) ^ (la & 7)) * 16 + (lg & 1) * 8,
      ((3 * 2 + (lg >> 1)) ^ (la & 7)) * 16 + (lg & 1) * 8};
  const int swzR0 = (lg ^ (la & 7)) * 16;        // read chunk lg   (keys 8lg..)
  const int swzR1 = ((4 + lg) ^ (la & 7)) * 16;  // read chunk 4+lg (keys 32+8lg..)

  // one subtile: S^T -> static-max softmax -> Ps (swizzled) -> PV
  auto computeTile = [&](const char* KsB, const char* VsB) {
    f32x4 s[4] = {};
#pragma unroll
    for (int nf = 0; nf < 4; ++nf) {
      const int kr = nf * 16 + la;
      const short8 kf0 = *(const short8*)(KsB + kr * 128 + ((lg ^ (kr & 7)) * 16));
      const short8 kf1 = *(const short8*)(KsB + kr * 128 + (((4 + lg) ^ (kr & 7)) * 16));
      s[nf] = MFMA16(kf0, qa0, s[nf]);
      s[nf] = MFMA16(kf1, qa1, s[nf]);
    }
    // order vs previous subtile's Ps reads (same-wave LDS reuse)
    asm volatile("" ::: "memory");
#pragma unroll
    for (int nf = 0; nf < 4; ++nf) {
      float e[4];
#pragma unroll
      for (int r = 0; r < 4; ++r)
        e[r] = exp2f(__builtin_fmaf(s[nf][r], SC, -M));
      lsum += (e[0] + e[1]) + (e[2] + e[3]);
      union { __hip_bfloat162 hh[2]; u16x4 v; } pk;
      pk.hh[0] = __float22bfloat162_rn(float2{e[0], e[1]});
      pk.hh[1] = __float22bfloat162_rn(float2{e[2], e[3]});
      *(u16x4*)(psBase + swzW[nf]) = pk.v;
    }
    asm volatile("" ::: "memory");
    const short8 pa0 = *(const short8*)(psBase + swzR0);
    const short8 pa1 = *(const short8*)(psBase + swzR1);
#pragma unroll
    for (int df = 0; df < 4; ++df) {
      const int vr = df * 16 + la;
      const short8 vf0 = *(const short8*)(VsB + vr * 128 + ((lg ^ (vr & 7)) * 16));
      const short8 vf1 = *(const short8*)(VsB + vr * 128 + (((4 + lg) ^ (vr & 7)) * 16));
      accO[df] = MFMA16(pa0, vf0, accO[df]);
      accO[df] = MFMA16(pa1, vf1, accO[df]);
    }
  };

  for (int kb = 0; kb < 2048; kb += 128) {
    __syncthreads();
    // stage BOTH subtiles inside the proven barrier sandwich
    load_lds16(k0p + (size_t)kb * 3072, (char*)Ks[0] + w * 1024);
    load_lds16(k1p + (size_t)kb * 3072, (char*)Ks[0] + w * 1024 + 4096);
    load_lds16(v0p + kb, (char*)Vs[0] + w * 1024);
    load_lds16(v1p + kb, (char*)Vs[0] + w * 1024 + 4096);
    load_lds16(k0p + (size_t)(kb + 64) * 3072, (char*)Ks[1] + w * 1024);
    load_lds16(k1p + (size_t)(kb + 64) * 3072, (char*)Ks[1] + w * 1024 + 4096);
    load_lds16(v0p + kb + 64, (char*)Vs[1] + w * 1024);
    load_lds16(v1p + kb + 64, (char*)Vs[1] + w * 1024 + 4096);
    __syncthreads();
    computeTile((const char*)Ks[0], (const char*)Vs[0]);
    computeTile((const char*)Ks[1], (const char*)Vs[1]);
  }
  // lsum: reduce the 4 lg-copies of q=la, broadcast to C-layout rows
  lsum += __shfl_xor(lsum, 16);
  lsum += __shfl_xor(lsum, 32);
#pragma unroll
  for (int r = 0; r < 4; ++r) {
    const float inv = 1.f / __shfl(lsum, lg * 4 + r);  // lane lg*4+r (la=lg*4+r) holds q's total
    const int orow = q0 + w * 16 + lg * 4 + r;
    unsigned short* op = outb + (size_t)(b * 2048 + orow) * 1024 + h * 64 + la;
#pragma unroll
    for (int df = 0; df < 4; ++df) op[df * 16] = f2bf(accO[df][r] * inv);
  }
}

// ---------------------------------------------------------------------------
extern "C" void kernel_launch(void* const* d_in, const int* in_sizes, int n_in,
                              void* d_out, int out_size, void* d_ws, size_t ws_size,
                              hipStream_t stream) {
  const float* x     = (const float*)d_in[0];
  const float* wqkv  = (const float*)d_in[1];
  const float* bqkv  = (const float*)d_in[2];
  const float* qnw   = (const float*)d_in[3];
  const float* knw   = (const float*)d_in[4];
  const float* wproj = (const float*)d_in[5];
  const float* bproj = (const float*)d_in[6];

  char* p = (char*)d_ws;
  unsigned short* xb     = (unsigned short*)p; p += (size_t)4096 * 1024 * 2;  // 8 MB
  unsigned short* wqkvb  = (unsigned short*)p; p += (size_t)3072 * 1024 * 2;  // 6 MB
  unsigned short* wprojb = (unsigned short*)p; p += (size_t)1024 * 1024 * 2;  // 2 MB
  unsigned short* qkvb   = (unsigned short*)p; p += (size_t)4096 * 3072 * 2;  // 24 MB
  unsigned short* vT     = (unsigned short*)p; p += (size_t)32 * 64 * 2048 * 2; // 8 MB
  unsigned short* aout   = (unsigned short*)p; p += (size_t)4096 * 1024 * 2;  // 8 MB

  convert_all<<<8192, 256, 0, stream>>>(x, wqkv, wproj, xb, wqkvb, wprojb);
  gemm_nt<true><<<dim3(24, 32), 256, 0, stream>>>(xb, wqkvb, bqkv, qkvb, 4096, 3072, 1024);
  rmsnorm_qk<<<4096, 256, 0, stream>>>(qkvb, qnw, knw);
  transpose_v<<<dim3(32, 32), 256, 0, stream>>>(qkvb, vT);
  attn_fwd<<<dim3(32, 32), 256, 0, stream>>>(qkvb, vT, aout);
  gemm_nt<false><<<dim3(8, 32), 256, 0, stream>>>(aout, wprojb, bproj, d_out, 4096, 1024, 1024);
}

// Round 14
// 131.609 us; speedup vs baseline: 1.1563x; 1.1563x over previous
//
#include <hip/hip_runtime.h>
#include <hip/hip_bf16.h>

typedef __attribute__((ext_vector_type(8))) short short8;           // 8 bf16 (MFMA operand)
typedef __attribute__((ext_vector_type(8))) unsigned short ushort8; // data movement
typedef __attribute__((ext_vector_type(4))) float f32x4;
typedef __attribute__((ext_vector_type(4))) unsigned short u16x4;

#define MFMA16(a, b, c) __builtin_amdgcn_mfma_f32_16x16x32_bf16(a, b, c, 0, 0, 0)

__device__ __forceinline__ unsigned short f2bf(float f) {
  union { float f; unsigned u; } x; x.f = f;
  unsigned r = x.u + 0x7FFFu + ((x.u >> 16) & 1u);  // RNE
  return (unsigned short)(r >> 16);
}
__device__ __forceinline__ float bf2f(unsigned short h) {
  union { unsigned u; float f; } x; x.u = ((unsigned)h) << 16;
  return x.f;
}
__device__ __forceinline__ void load_lds16(const void* g, void* l) {
  __builtin_amdgcn_global_load_lds((const __attribute__((address_space(1))) void*)g,
                                   (__attribute__((address_space(3))) void*)l, 16, 0, 0);
}

// ---------------------------------------------------------------------------
// 1) fp32 -> bf16 conversion for x, w_qkv, w_proj
// ---------------------------------------------------------------------------
__global__ __launch_bounds__(256) void convert_all(
    const float* __restrict__ x, const float* __restrict__ wqkv, const float* __restrict__ wproj,
    unsigned short* __restrict__ xb, unsigned short* __restrict__ wqkvb,
    unsigned short* __restrict__ wprojb) {
  int i = blockIdx.x * 256 + threadIdx.x;
  const float4* src; unsigned short* dst; int o;
  if (i < 1048576) { src = (const float4*)x; dst = xb; o = i; }
  else if (i < 1048576 + 786432) { src = (const float4*)wqkv; dst = wqkvb; o = i - 1048576; }
  else { src = (const float4*)wproj; dst = wprojb; o = i - (1048576 + 786432); }
  float4 v = src[o];
  u16x4 r; r.x = f2bf(v.x); r.y = f2bf(v.y); r.z = f2bf(v.z); r.w = f2bf(v.w);
  *(u16x4*)(dst + (size_t)o * 4) = r;
}

// ---------------------------------------------------------------------------
// 2) NT GEMM: C[M,N] = A[M,K]*B[N,K]^T + bias. 128x128 tile, BK=32, 4 waves.
//    MODE 0: fp32 C out (out-proj).
//    MODE 1: QKV fused epilogue — q/k parts: RMSNorm (fp32) -> bf16 qkv;
//            v part: direct transpose-store to vT[bh][d][n] (skip qkv write).
// ---------------------------------------------------------------------------
template <int MODE>
__global__ __launch_bounds__(256) void gemm_nt(
    const unsigned short* __restrict__ A, const unsigned short* __restrict__ Bm,
    const float* __restrict__ bias, void* __restrict__ Cout, int M, int N, int K,
    const float* __restrict__ qnw, const float* __restrict__ knw,
    unsigned short* __restrict__ vT) {
  __shared__ unsigned short As[128 * 32];
  __shared__ unsigned short Bs[128 * 32];
  const int t = threadIdx.x, w = t >> 6, l = t & 63;
  const int la = l & 15, lg = l >> 4;
  const int wm = w >> 1, wn = w & 1;
  const int m0 = blockIdx.y * 128, n0 = blockIdx.x * 128;

  const int r0 = t >> 2, c0 = (t & 3) ^ ((r0 >> 1) & 3);
  const int r1 = r0 + 64, c1 = (t & 3) ^ ((r1 >> 1) & 3);
  const unsigned short* a0 = A + (size_t)(m0 + r0) * K + c0 * 8;
  const unsigned short* a1 = A + (size_t)(m0 + r1) * K + c1 * 8;
  const unsigned short* b0 = Bm + (size_t)(n0 + r0) * K + c0 * 8;
  const unsigned short* b1 = Bm + (size_t)(n0 + r1) * K + c1 * 8;
  char* ldsA0 = (char*)As + w * 1024;
  char* ldsA1 = (char*)As + w * 1024 + 4096;
  char* ldsB0 = (char*)Bs + w * 1024;
  char* ldsB1 = (char*)Bs + w * 1024 + 4096;

  f32x4 acc[4][4] = {};
  int offA[4], offB[4];
#pragma unroll
  for (int f = 0; f < 4; ++f) {
    int ra = wm * 64 + f * 16 + la;
    offA[f] = ra * 64 + ((lg ^ ((ra >> 1) & 3)) * 16);
    int rb = wn * 64 + f * 16 + la;
    offB[f] = rb * 64 + ((lg ^ ((rb >> 1) & 3)) * 16);
  }

  for (int kt = 0; kt < K; kt += 32) {
    __syncthreads();
    load_lds16(a0 + kt, ldsA0);
    load_lds16(a1 + kt, ldsA1);
    load_lds16(b0 + kt, ldsB0);
    load_lds16(b1 + kt, ldsB1);
    __syncthreads();
    short8 af[4], bf[4];
#pragma unroll
    for (int f = 0; f < 4; ++f) af[f] = *(const short8*)((const char*)As + offA[f]);
#pragma unroll
    for (int f = 0; f < 4; ++f) bf[f] = *(const short8*)((const char*)Bs + offB[f]);
#pragma unroll
    for (int mf = 0; mf < 4; ++mf)
#pragma unroll
      for (int nf = 0; nf < 4; ++nf)
        acc[mf][nf] = MFMA16(af[mf], bf[nf], acc[mf][nf]);
  }

  const int colb = n0 + wn * 64 + la;
  const int rowb = m0 + wm * 64 + lg * 4;

  // add bias once (fp32)
#pragma unroll
  for (int nf = 0; nf < 4; ++nf) {
    const float bv = bias[colb + nf * 16];
#pragma unroll
    for (int mf = 0; mf < 4; ++mf)
#pragma unroll
      for (int r = 0; r < 4; ++r) acc[mf][nf][r] += bv;
  }

  if (MODE == 0) {
#pragma unroll
    for (int nf = 0; nf < 4; ++nf) {
      const int col = colb + nf * 16;
#pragma unroll
      for (int mf = 0; mf < 4; ++mf)
#pragma unroll
        for (int r = 0; r < 4; ++r)
          ((float*)Cout)[(size_t)(rowb + mf * 16 + r) * N + col] = acc[mf][nf][r];
    }
  } else {
    const int part = n0 >> 10;  // 0=q, 1=k, 2=v (col tile of 128 within one part)
    if (part < 2) {
      // fused RMSNorm: this wave's 64 cols = one head; rows are (mf,r)
      const float* nw = part ? knw : qnw;
      float nwv[4];
#pragma unroll
      for (int nf = 0; nf < 4; ++nf) nwv[nf] = nw[la + nf * 16];
#pragma unroll
      for (int mf = 0; mf < 4; ++mf)
#pragma unroll
        for (int r = 0; r < 4; ++r) {
          float ss = acc[mf][0][r] * acc[mf][0][r];
#pragma unroll
          for (int nf = 1; nf < 4; ++nf) ss = __builtin_fmaf(acc[mf][nf][r], acc[mf][nf][r], ss);
          ss += __shfl_xor(ss, 1); ss += __shfl_xor(ss, 2);
          ss += __shfl_xor(ss, 4); ss += __shfl_xor(ss, 8);
          const float rs = rsqrtf(ss * (1.f / 64.f) + 1e-6f);
#pragma unroll
          for (int nf = 0; nf < 4; ++nf) acc[mf][nf][r] *= rs * nwv[nf];
        }
    }
    if (part < 2) {
#pragma unroll
      for (int nf = 0; nf < 4; ++nf) {
        const int col = colb + nf * 16;
#pragma unroll
        for (int mf = 0; mf < 4; ++mf)
#pragma unroll
          for (int r = 0; r < 4; ++r)
            ((unsigned short*)Cout)[(size_t)(rowb + mf * 16 + r) * N + col] = f2bf(acc[mf][nf][r]);
      }
    } else {
      // v: transpose-store to vT[(b*16+h)*64+d][n], 4 consecutive n per lane
#pragma unroll
      for (int nf = 0; nf < 4; ++nf) {
        const int col = colb + nf * 16;         // 2048 + h*64 + d
        const int h = (col >> 6) & 15;
        const int d = la + nf * 16;             // col & 63
#pragma unroll
        for (int mf = 0; mf < 4; ++mf) {
          const int row = rowb + mf * 16;       // rows row..row+3
          const int b = row >> 11, n = row & 2047;
          u16x4 o;
#pragma unroll
          for (int r = 0; r < 4; ++r) o[r] = f2bf(acc[mf][nf][r]);
          *(u16x4*)(vT + ((size_t)(b * 16 + h) * 64 + d) * 2048 + n) = o;
        }
      }
    }
  }
}

// ---------------------------------------------------------------------------
// 5) Flash attention — round-11 PASS structure verbatim; only change:
//    exp2f -> __builtin_amdgcn_exp2f (raw v_exp_f32; inputs bounded [-24,0]).
// ---------------------------------------------------------------------------
__global__ __launch_bounds__(256) void attn_fwd(
    const unsigned short* __restrict__ qkv, const unsigned short* __restrict__ vT,
    unsigned short* __restrict__ outb) {
  __shared__ unsigned short Ks[64 * 64];
  __shared__ unsigned short Vs[64 * 64];
  __shared__ unsigned short Ps[4][16][76];
  const int t = threadIdx.x, w = t >> 6, l = t & 63;
  const int la = l & 15, lg = l >> 4;
  const int q0 = blockIdx.x * 64, bh = blockIdx.y;
  const int b = bh >> 4, h = bh & 15;

  // Q fragment (B-operand of swapped QK^T: col=q=la, k=d=lg*8+j)
  const int qrow = q0 + w * 16 + la;
  const unsigned short* qp = qkv + (size_t)(b * 2048 + qrow) * 3072 + h * 64;
  const short8 qa0 = *(const short8*)(qp + lg * 8);
  const short8 qa1 = *(const short8*)(qp + 32 + lg * 8);

  // staging sources: 512 chunks/tile, rows of 8 chunks, swizzle c ^= (r&7)
  const int r0 = t >> 3, c0 = (t & 7) ^ (r0 & 7);
  const int r1 = r0 + 32, c1 = (t & 7) ^ (r1 & 7);
  const unsigned short* k0p = qkv + (size_t)(b * 2048 + r0) * 3072 + 1024 + h * 64 + c0 * 8;
  const unsigned short* k1p = qkv + (size_t)(b * 2048 + r1) * 3072 + 1024 + h * 64 + c1 * 8;
  const unsigned short* v0p = vT + (size_t)(bh * 64 + r0) * 2048 + c0 * 8;
  const unsigned short* v1p = vT + (size_t)(bh * 64 + r1) * 2048 + c1 * 8;

  f32x4 accO[4] = {};
  float lsum = 0.f;
  const float SC = 0.125f * 1.44269504f;  // scale * log2(e)
  const float M = 12.0f;                  // static max bound (|q.k|<=64.5 -> |s*SC|<=11.63)

  for (int kb = 0; kb < 2048; kb += 64) {
    __syncthreads();
    load_lds16(k0p + (size_t)kb * 3072, (char*)Ks + w * 1024);
    load_lds16(k1p + (size_t)kb * 3072, (char*)Ks + w * 1024 + 4096);
    load_lds16(v0p + kb, (char*)Vs + w * 1024);
    load_lds16(v1p + kb, (char*)Vs + w * 1024 + 4096);
    __syncthreads();

    // S^T = K Q^T : A = K rows (keys), B = Q cols (q).
    f32x4 s[4] = {};
#pragma unroll
    for (int nf = 0; nf < 4; ++nf) {
      const int kr = nf * 16 + la;
      const short8 kf0 = *(const short8*)((const char*)Ks + kr * 128 + ((lg ^ (kr & 7)) * 16));
      const short8 kf1 = *(const short8*)((const char*)Ks + kr * 128 + (((4 + lg) ^ (kr & 7)) * 16));
      s[nf] = MFMA16(kf0, qa0, s[nf]);
      s[nf] = MFMA16(kf1, qa1, s[nf]);
    }
    // static-max softmax, lane-local; native exp2 + packed bf16 cvt
#pragma unroll
    for (int nf = 0; nf < 4; ++nf) {
      float e[4];
#pragma unroll
      for (int r = 0; r < 4; ++r)
        e[r] = __builtin_amdgcn_exp2f(__builtin_fmaf(s[nf][r], SC, -M));
      lsum += (e[0] + e[1]) + (e[2] + e[3]);
      union { __hip_bfloat162 hh[2]; u16x4 v; } pk;
      pk.hh[0] = __float22bfloat162_rn(float2{e[0], e[1]});
      pk.hh[1] = __float22bfloat162_rn(float2{e[2], e[3]});
      *(u16x4*)&Ps[w][la][nf * 16 + lg * 4] = pk.v;  // row=q(la), col=key
    }
    // compiler fence: forbid hoisting P reads above P writes (same-wave LDS RAW)
    asm volatile("" ::: "memory");
    // P A-fragments (row=q=la, k=key=lg*8+j)
    const short8 pa0 = *(const short8*)&Ps[w][la][lg * 8];
    const short8 pa1 = *(const short8*)&Ps[w][la][32 + lg * 8];

    // out += P V : P as A (rows q), V^T rows as B (cols d), K=32 x2
#pragma unroll
    for (int df = 0; df < 4; ++df) {
      const int vr = df * 16 + la;
      const short8 vf0 = *(const short8*)((const char*)Vs + vr * 128 + ((lg ^ (vr & 7)) * 16));
      const short8 vf1 = *(const short8*)((const char*)Vs + vr * 128 + (((4 + lg) ^ (vr & 7)) * 16));
      accO[df] = MFMA16(pa0, vf0, accO[df]);
      accO[df] = MFMA16(pa1, vf1, accO[df]);
    }
  }
  // lsum: reduce the 4 lg-copies of q=la, broadcast to C-layout rows
  lsum += __shfl_xor(lsum, 16);
  lsum += __shfl_xor(lsum, 32);
#pragma unroll
  for (int r = 0; r < 4; ++r) {
    const float inv = 1.f / __shfl(lsum, lg * 4 + r);  // lane lg*4+r (la=lg*4+r) holds q's total
    const int orow = q0 + w * 16 + lg * 4 + r;
    unsigned short* op = outb + (size_t)(b * 2048 + orow) * 1024 + h * 64 + la;
#pragma unroll
    for (int df = 0; df < 4; ++df) op[df * 16] = f2bf(accO[df][r] * inv);
  }
}

// ---------------------------------------------------------------------------
extern "C" void kernel_launch(void* const* d_in, const int* in_sizes, int n_in,
                              void* d_out, int out_size, void* d_ws, size_t ws_size,
                              hipStream_t stream) {
  const float* x     = (const float*)d_in[0];
  const float* wqkv  = (const float*)d_in[1];
  const float* bqkv  = (const float*)d_in[2];
  const float* qnw   = (const float*)d_in[3];
  const float* knw   = (const float*)d_in[4];
  const float* wproj = (const float*)d_in[5];
  const float* bproj = (const float*)d_in[6];

  char* p = (char*)d_ws;
  unsigned short* xb     = (unsigned short*)p; p += (size_t)4096 * 1024 * 2;  // 8 MB
  unsigned short* wqkvb  = (unsigned short*)p; p += (size_t)3072 * 1024 * 2;  // 6 MB
  unsigned short* wprojb = (unsigned short*)p; p += (size_t)1024 * 1024 * 2;  // 2 MB
  unsigned short* qkvb   = (unsigned short*)p; p += (size_t)4096 * 3072 * 2;  // 24 MB
  unsigned short* vT     = (unsigned short*)p; p += (size_t)32 * 64 * 2048 * 2; // 8 MB
  unsigned short* aout   = (unsigned short*)p; p += (size_t)4096 * 1024 * 2;  // 8 MB

  convert_all<<<8192, 256, 0, stream>>>(x, wqkv, wproj, xb, wqkvb, wprojb);
  gemm_nt<1><<<dim3(24, 32), 256, 0, stream>>>(xb, wqkvb, bqkv, qkvb, 4096, 3072, 1024,
                                               qnw, knw, vT);
  attn_fwd<<<dim3(32, 32), 256, 0, stream>>>(qkvb, vT, aout);
  gemm_nt<0><<<dim3(8, 32), 256, 0, stream>>>(aout, wprojb, bproj, d_out, 4096, 1024, 1024,
                                              nullptr, nullptr, nullptr);
}